// Round 3
// baseline (182.910 us; speedup 1.0000x reference)
//
#include <hip/hip_runtime.h>
#include <math.h>

// Problem constants (from reference)
#define N_SAMPLES 32768
#define N_FRAMES  128
#define N_EVENTS  16
#define MODEL_DIM 128
#define N_FREQS   16
#define POS_DIM   33          // 2*16 + 1
#define N_ROWS    512         // B*E = 32*16
#define SPLIT     4           // blocks per row in fused kernel

// ws layout: [0, 128*33*4) pos_hat floats

// ---------------------------------------------------------------------------
// Kernel 1: normalized positional encodings (128 x 33). One block per frame;
// lane j computes exactly ONE double sin/cos. Numerics match numpy:
// x = f32(linspace(-pi,pi,128)) computed in double; arg = 2^i * x exact via
// ldexp; sin/cos in double, rounded to f32; norm accumulated in double.
// ---------------------------------------------------------------------------
__global__ __launch_bounds__(64) void pos_kernel(float* __restrict__ pos_hat) {
    int f = blockIdx.x;                        // frame 0..127
    int j = threadIdx.x;                       // feature 0..32 (33..63 idle)

    __shared__ float s_feat[POS_DIM];
    __shared__ float s_inv;

    double step = (2.0 * M_PI) / 127.0;
    double xd = -M_PI + (double)f * step;
    if (f == N_FRAMES - 1) xd = M_PI;          // linspace endpoint exact
    float x = (float)xd;

    if (j < POS_DIM) {
        float v;
        if (j == 0) {
            v = x;
        } else {
            int i = (j - 1) >> 1;              // frequency index
            double arg = ldexp((double)x, i);  // x * 2^i, exact
            v = (j & 1) ? (float)sin(arg) : (float)cos(arg);
        }
        s_feat[j] = v;
    }
    __syncthreads();

    if (j == 0) {
        double nrm = 0.0;
        for (int k = 0; k < POS_DIM; ++k)
            nrm += (double)s_feat[k] * (double)s_feat[k];
        s_inv = 1.0f / ((float)sqrt(nrm) + 1e-8f);
    }
    __syncthreads();

    if (j < POS_DIM) pos_hat[f * POS_DIM + j] = s_feat[j] * s_inv;
}

// ---------------------------------------------------------------------------
// Kernel 2 (fused argmax + shift): grid (SPLIT, 512), 1024 threads.
// Each block redundantly computes its row's argmax (cheap, ~1 us, overlapped
// across 2048 blocks; W/pos_hat stay L2-resident), then streams its quarter
// of the row: out[row,t] = (t >= d) ? stems[row,t-d]/256 : 0.
// Numerics identical to previous passing version: projection p = TL@W + b in
// double -> f32; frame dots in double; tie-break lowest frame index.
// d is a multiple of 256; float4 chunks never straddle d.
// ---------------------------------------------------------------------------
__global__ __launch_bounds__(1024) void fused_kernel(
    const float* __restrict__ tl,        // (512,128)
    const float* __restrict__ W,         // (128,33) row-major
    const float* __restrict__ b,         // (33)
    const float* __restrict__ pos_hat,   // (128,33)
    const float* __restrict__ stems,     // (512,32768)
    float*       __restrict__ out)       // (512,32768)
{
    __shared__ float  s_tl[MODEL_DIM];
    __shared__ float  s_p[POS_DIM];
    __shared__ double sv[N_FRAMES];
    __shared__ int    si[N_FRAMES];
    __shared__ int    s_d;

    int row = blockIdx.y;
    int t = threadIdx.x;

    if (t < MODEL_DIM) s_tl[t] = tl[(size_t)row * MODEL_DIM + t];
    __syncthreads();

    if (t < POS_DIM) {
        double acc = (double)b[t];
        for (int k = 0; k < MODEL_DIM; ++k)
            acc += (double)s_tl[k] * (double)W[k * POS_DIM + t];
        s_p[t] = (float)acc;
    }
    __syncthreads();

    if (t < N_FRAMES) {
        double s = 0.0;
        for (int j = 0; j < POS_DIM; ++j)
            s += (double)s_p[j] * (double)pos_hat[t * POS_DIM + j];
        sv[t] = s;
        si[t] = t;
    }
    __syncthreads();

    for (int off = 64; off > 0; off >>= 1) {
        if (t < off) {
            double ov = sv[t + off];
            int    oi = si[t + off];
            if (ov > sv[t] || (ov == sv[t] && oi < si[t])) {
                sv[t] = ov;
                si[t] = oi;
            }
        }
        __syncthreads();
    }
    if (t == 0) s_d = si[0] * (N_SAMPLES / N_FRAMES);
    __syncthreads();

    int d = s_d;
    const float4* src = (const float4*)(stems + (size_t)row * N_SAMPLES);
    float4*       dst = (float4*)(out + (size_t)row * N_SAMPLES);
    const float sc = 1.0f / 256.0f;

    int base = blockIdx.x * (N_SAMPLES / SPLIT);   // 8192 samples per block
#pragma unroll
    for (int it = 0; it < (N_SAMPLES / SPLIT) / (1024 * 4); ++it) {  // 2 iters
        int tt = base + (it * 1024 + t) * 4;
        float4 v;
        if (tt >= d) {
            v = src[(tt - d) >> 2];
            v.x *= sc; v.y *= sc; v.z *= sc; v.w *= sc;
        } else {
            v = make_float4(0.f, 0.f, 0.f, 0.f);
        }
        dst[tt >> 2] = v;
    }
}

extern "C" void kernel_launch(void* const* d_in, const int* in_sizes, int n_in,
                              void* d_out, int out_size, void* d_ws, size_t ws_size,
                              hipStream_t stream) {
    const float* tl    = (const float*)d_in[0];  // time_latent (512,128)
    const float* stems = (const float*)d_in[1];  // (32,16,32768)
    // d_in[2] = targets — unused by the reference
    const float* W     = (const float*)d_in[3];  // (128,33)
    const float* b     = (const float*)d_in[4];  // (33)
    float* out = (float*)d_out;

    float* pos_hat = (float*)d_ws;

    pos_kernel<<<N_FRAMES, 64, 0, stream>>>(pos_hat);
    fused_kernel<<<dim3(SPLIT, N_ROWS), 1024, 0, stream>>>(tl, W, b, pos_hat, stems, out);
}

// Round 4
// 175.264 us; speedup vs baseline: 1.0436x; 1.0436x over previous
//
#include <hip/hip_runtime.h>
#include <math.h>

// Problem constants (from reference)
#define N_SAMPLES 32768
#define N_FRAMES  128
#define N_EVENTS  16
#define MODEL_DIM 128
#define N_FREQS   16
#define POS_DIM   33          // 2*16 + 1
#define N_ROWS    512         // B*E = 32*16
#define SPLIT     8           // blocks per row in streaming kernel

// ws layout:
//   [0, 16896)        pos_hat  (128*33 floats)
//   [17408, 84992)    p        (512*33 floats), 512B-aligned start
#define WS_P_OFF 17408

// ---------------------------------------------------------------------------
// Kernel 1 (setup): blocks 0..127 build normalized pos encodings (one frame
// each, one double sin/cos per lane); blocks 128..639 build the projection
// p[row] = TL_row @ W + b (double acc, serial k order — bit-identical to the
// passing R2 kernel). The two halves are independent; merging them saves a
// launch. 128 threads/block.
// ---------------------------------------------------------------------------
__global__ __launch_bounds__(128) void setup_kernel(
    const float* __restrict__ tl,        // (512,128)
    const float* __restrict__ W,         // (128,33) row-major
    const float* __restrict__ b,         // (33)
    float* __restrict__ pos_hat,         // (128,33)
    float* __restrict__ p_out)           // (512,33)
{
    int bid = blockIdx.x;
    int t = threadIdx.x;

    if (bid < N_FRAMES) {
        // --- positional encoding for frame f ---
        int f = bid;
        __shared__ float s_feat[POS_DIM];
        __shared__ float s_inv;

        double step = (2.0 * M_PI) / 127.0;
        double xd = -M_PI + (double)f * step;
        if (f == N_FRAMES - 1) xd = M_PI;      // linspace endpoint exact
        float x = (float)xd;

        if (t < POS_DIM) {
            float v;
            if (t == 0) {
                v = x;
            } else {
                int i = (t - 1) >> 1;          // frequency index
                double arg = ldexp((double)x, i);  // x * 2^i, exact
                v = (t & 1) ? (float)sin(arg) : (float)cos(arg);
            }
            s_feat[t] = v;
        }
        __syncthreads();

        if (t == 0) {
            double nrm = 0.0;
            for (int k = 0; k < POS_DIM; ++k)
                nrm += (double)s_feat[k] * (double)s_feat[k];
            s_inv = 1.0f / ((float)sqrt(nrm) + 1e-8f);
        }
        __syncthreads();

        if (t < POS_DIM) pos_hat[f * POS_DIM + t] = s_feat[t] * s_inv;
    } else {
        // --- projection for row = bid - 128 ---
        int row = bid - N_FRAMES;
        __shared__ float s_tl[MODEL_DIM];

        s_tl[t] = tl[(size_t)row * MODEL_DIM + t];
        __syncthreads();

        if (t < POS_DIM) {
            double acc = (double)b[t];
            for (int k = 0; k < MODEL_DIM; ++k)
                acc += (double)s_tl[k] * (double)W[k * POS_DIM + t];
            p_out[row * POS_DIM + t] = (float)acc;
        }
    }
}

// ---------------------------------------------------------------------------
// Kernel 2 (fused argmax + shift): grid (SPLIT, 512), 256 threads.
// Shallow redundant preamble per block: load p[row] (33 floats), frame dots
// (33 double FMAs, lane t<128), 7-round tree reduce — ~0.2 us, hidden by
// streaming of co-resident blocks (8 blocks/CU at 256 thr). Then stream
// 4096 samples: out[row,t] = (t >= d) ? stems[row,t-d]/256 : 0.
// Frame-dot and reduce orders bit-identical to R2. Tie-break: lowest index.
// d is a multiple of 256; float4 chunks never straddle d.
// ---------------------------------------------------------------------------
__global__ __launch_bounds__(256) void shift_kernel(
    const float* __restrict__ p,         // (512,33)
    const float* __restrict__ pos_hat,   // (128,33)
    const float* __restrict__ stems,     // (512,32768)
    float*       __restrict__ out)       // (512,32768)
{
    __shared__ float  s_p[POS_DIM];
    __shared__ double sv[N_FRAMES];
    __shared__ int    si[N_FRAMES];
    __shared__ int    s_d;

    int row = blockIdx.y;
    int t = threadIdx.x;

    if (t < POS_DIM) s_p[t] = p[row * POS_DIM + t];
    __syncthreads();

    if (t < N_FRAMES) {
        double s = 0.0;
        for (int j = 0; j < POS_DIM; ++j)
            s += (double)s_p[j] * (double)pos_hat[t * POS_DIM + j];
        sv[t] = s;
        si[t] = t;
    }
    __syncthreads();

    for (int off = 64; off > 0; off >>= 1) {
        if (t < off) {
            double ov = sv[t + off];
            int    oi = si[t + off];
            if (ov > sv[t] || (ov == sv[t] && oi < si[t])) {
                sv[t] = ov;
                si[t] = oi;
            }
        }
        __syncthreads();
    }
    if (t == 0) s_d = si[0] * (N_SAMPLES / N_FRAMES);
    __syncthreads();

    int d = s_d;
    const float4* src = (const float4*)(stems + (size_t)row * N_SAMPLES);
    float4*       dst = (float4*)(out + (size_t)row * N_SAMPLES);
    const float sc = 1.0f / 256.0f;

    int base = blockIdx.x * (N_SAMPLES / SPLIT);   // 4096 samples per block
#pragma unroll
    for (int it = 0; it < (N_SAMPLES / SPLIT) / (256 * 4); ++it) {  // 4 iters
        int tt = base + (it * 256 + t) * 4;
        float4 v;
        if (tt >= d) {
            v = src[(tt - d) >> 2];
            v.x *= sc; v.y *= sc; v.z *= sc; v.w *= sc;
        } else {
            v = make_float4(0.f, 0.f, 0.f, 0.f);
        }
        dst[tt >> 2] = v;
    }
}

extern "C" void kernel_launch(void* const* d_in, const int* in_sizes, int n_in,
                              void* d_out, int out_size, void* d_ws, size_t ws_size,
                              hipStream_t stream) {
    const float* tl    = (const float*)d_in[0];  // time_latent (512,128)
    const float* stems = (const float*)d_in[1];  // (32,16,32768)
    // d_in[2] = targets — unused by the reference
    const float* W     = (const float*)d_in[3];  // (128,33)
    const float* b     = (const float*)d_in[4];  // (33)
    float* out = (float*)d_out;

    float* pos_hat = (float*)d_ws;
    float* p       = (float*)((char*)d_ws + WS_P_OFF);

    setup_kernel<<<N_FRAMES + N_ROWS, 128, 0, stream>>>(tl, W, b, pos_hat, p);
    shift_kernel<<<dim3(SPLIT, N_ROWS), 256, 0, stream>>>(p, pos_hat, stems, out);
}

// Round 5
// 169.619 us; speedup vs baseline: 1.0784x; 1.0333x over previous
//
#include <hip/hip_runtime.h>
#include <math.h>

// Problem constants (from reference)
#define N_SAMPLES 32768
#define N_FRAMES  128
#define N_EVENTS  16
#define MODEL_DIM 128
#define N_FREQS   16
#define POS_DIM   33          // 2*16 + 1
#define N_ROWS    512         // B*E = 32*16

// ws layout:
//   [0, 16896)        pos_hat  (128*33 floats)
//   [17408, 84992)    p        (512*33 floats)
//   [85504, 87552)    dvals    (512 ints)
#define WS_P_OFF 17408
#define WS_D_OFF 85504

// ---------------------------------------------------------------------------
// Kernel 1 (setup): blocks 0..127 build normalized pos encodings (one frame
// each, one double sin/cos per lane); blocks 128..639 build the projection
// p[row] = TL_row @ W + b (double acc, serial k order). Halves are
// independent — merged to save a launch (validated in R4). Numerics match
// numpy: x = f32(linspace(-pi,pi,128)) via double; arg = 2^i*x exact (ldexp);
// sin/cos in double -> f32; norms in double.
// ---------------------------------------------------------------------------
__global__ __launch_bounds__(128) void setup_kernel(
    const float* __restrict__ tl,        // (512,128)
    const float* __restrict__ W,         // (128,33) row-major
    const float* __restrict__ b,         // (33)
    float* __restrict__ pos_hat,         // (128,33)
    float* __restrict__ p_out)           // (512,33)
{
    int bid = blockIdx.x;
    int t = threadIdx.x;

    if (bid < N_FRAMES) {
        int f = bid;
        __shared__ float s_feat[POS_DIM];
        __shared__ float s_inv;

        double step = (2.0 * M_PI) / 127.0;
        double xd = -M_PI + (double)f * step;
        if (f == N_FRAMES - 1) xd = M_PI;      // linspace endpoint exact
        float x = (float)xd;

        if (t < POS_DIM) {
            float v;
            if (t == 0) {
                v = x;
            } else {
                int i = (t - 1) >> 1;              // frequency index
                double arg = ldexp((double)x, i);  // x * 2^i, exact
                v = (t & 1) ? (float)sin(arg) : (float)cos(arg);
            }
            s_feat[t] = v;
        }
        __syncthreads();

        if (t == 0) {
            double nrm = 0.0;
            for (int k = 0; k < POS_DIM; ++k)
                nrm += (double)s_feat[k] * (double)s_feat[k];
            s_inv = 1.0f / ((float)sqrt(nrm) + 1e-8f);
        }
        __syncthreads();

        if (t < POS_DIM) pos_hat[f * POS_DIM + t] = s_feat[t] * s_inv;
    } else {
        int row = bid - N_FRAMES;
        __shared__ float s_tl[MODEL_DIM];

        s_tl[t] = tl[(size_t)row * MODEL_DIM + t];
        __syncthreads();

        if (t < POS_DIM) {
            double acc = (double)b[t];
            for (int k = 0; k < MODEL_DIM; ++k)
                acc += (double)s_tl[k] * (double)W[k * POS_DIM + t];
            p_out[row * POS_DIM + t] = (float)acc;
        }
    }
}

// ---------------------------------------------------------------------------
// Kernel 2 (argmax): one block per row, 128 threads. Frame dots (double acc)
// + tree reduce, orders bit-identical to the passing R2 kernel. Tie-break:
// lowest frame index (jnp.argmax first occurrence). Writes d = argmax*256.
// ---------------------------------------------------------------------------
__global__ __launch_bounds__(128) void argmax_kernel(
    const float* __restrict__ p,         // (512,33)
    const float* __restrict__ pos_hat,   // (128,33)
    int* __restrict__ dout)              // (512)
{
    __shared__ float  s_p[POS_DIM];
    __shared__ double sv[N_FRAMES];
    __shared__ int    si[N_FRAMES];

    int row = blockIdx.x;
    int t = threadIdx.x;

    if (t < POS_DIM) s_p[t] = p[row * POS_DIM + t];
    __syncthreads();

    double s = 0.0;
    for (int j = 0; j < POS_DIM; ++j)
        s += (double)s_p[j] * (double)pos_hat[t * POS_DIM + j];
    sv[t] = s;
    si[t] = t;
    __syncthreads();

    for (int off = 64; off > 0; off >>= 1) {
        if (t < off) {
            double ov = sv[t + off];
            int    oi = si[t + off];
            if (ov > sv[t] || (ov == sv[t] && oi < si[t])) {
                sv[t] = ov;
                si[t] = oi;
            }
        }
        __syncthreads();
    }
    if (t == 0) dout[row] = si[0] * (N_SAMPLES / N_FRAMES);
}

// ---------------------------------------------------------------------------
// Kernel 3 (shift, zero preamble — R2's best-measured streaming kernel):
// out[row,t] = (t >= d) ? stems[row,t-d]/256 : 0.
// d is a multiple of 256; float4 chunks never straddle d.
// ---------------------------------------------------------------------------
__global__ __launch_bounds__(256) void shift_kernel(
    const float* __restrict__ stems,     // (512, 32768)
    const int*   __restrict__ dvals,     // (512)
    float*       __restrict__ out)       // (512, 32768)
{
    int row = blockIdx.y;
    int t = (blockIdx.x * 256 + threadIdx.x) * 4;
    int d = dvals[row];

    const float4* src = (const float4*)(stems + (size_t)row * N_SAMPLES);
    float4*       dst = (float4*)(out + (size_t)row * N_SAMPLES);

    float4 v;
    if (t >= d) {
        v = src[(t - d) >> 2];
        const float sc = 1.0f / 256.0f;
        v.x *= sc; v.y *= sc; v.z *= sc; v.w *= sc;
    } else {
        v = make_float4(0.f, 0.f, 0.f, 0.f);
    }
    dst[t >> 2] = v;
}

extern "C" void kernel_launch(void* const* d_in, const int* in_sizes, int n_in,
                              void* d_out, int out_size, void* d_ws, size_t ws_size,
                              hipStream_t stream) {
    const float* tl    = (const float*)d_in[0];  // time_latent (512,128)
    const float* stems = (const float*)d_in[1];  // (32,16,32768)
    // d_in[2] = targets — unused by the reference
    const float* W     = (const float*)d_in[3];  // (128,33)
    const float* b     = (const float*)d_in[4];  // (33)
    float* out = (float*)d_out;

    float* pos_hat = (float*)d_ws;
    float* p       = (float*)((char*)d_ws + WS_P_OFF);
    int*   dvals   = (int*)((char*)d_ws + WS_D_OFF);

    setup_kernel<<<N_FRAMES + N_ROWS, 128, 0, stream>>>(tl, W, b, pos_hat, p);
    argmax_kernel<<<N_ROWS, 128, 0, stream>>>(p, pos_hat, dvals);
    shift_kernel<<<dim3(N_SAMPLES / (256 * 4), N_ROWS), 256, 0, stream>>>(stems, dvals, out);
}